// Round 8
// baseline (251.255 us; speedup 1.0000x reference)
//
#include <hip/hip_runtime.h>
#include <cstdint>

typedef _Float16 half8 __attribute__((ext_vector_type(8)));
typedef float f32x4 __attribute__((ext_vector_type(4)));

#define HW_ (512*512)

// ---------------- weight transform: fp32 -> frag-linear fp16 --------------
// 8 layers: 0-3 rh (O=61,CIN=61), 4 hl0 (O=64,CIN=61), 5-7 hl (O=64,CIN=64).
// Per layer 36864 halfs: chunk ci = s*8 + kk*4 + m, 512 halfs per chunk.
// Element (lane,j): A[o = m*16 + (lane&15)][c = kk*32 + (lane>>4)*8 + j].
// Phase slice (s,kk) = 2048 contiguous halfs.
// Block 0 also zeroes the 32-half guard region ZG (OOB staging target).
__global__ __launch_bounds__(256) void wtrans_k(
    const float* __restrict__ rh_w, const float* __restrict__ hl0_w,
    const float* __restrict__ hl_w, _Float16* __restrict__ wt,
    _Float16* __restrict__ zg)
{
    if (blockIdx.x == 0 && threadIdx.x < 32) zg[threadIdx.x] = (_Float16)0.f;
    int t = blockIdx.x * 256 + threadIdx.x;
    if (t >= 8 * 4608) return;
    int layer = t / 4608;
    int r = t - layer * 4608;
    int lane = r & 63, ci = r >> 6;
    int m = ci & 3, kk = (ci >> 2) & 1, s = ci >> 3;
    int o = m * 16 + (lane & 15);
    int cb = kk * 32 + ((lane >> 4) & 3) * 8;
    const float* w; int O, CIN;
    if (layer < 4)      { w = rh_w + (size_t)layer * 61 * 61 * 9; O = 61; CIN = 61; }
    else if (layer == 4){ w = hl0_w;                              O = 64; CIN = 61; }
    else                { w = hl_w + (size_t)(layer - 5) * 64 * 64 * 9; O = 64; CIN = 64; }
    half8 v;
    #pragma unroll
    for (int j = 0; j < 8; ++j) {
        int c = cb + j;
        float f = (o < O && c < CIN) ? w[((size_t)o * CIN + c) * 9 + s] : 0.f;
        v[j] = (_Float16)f;
    }
    *(half8*)(wt + (size_t)layer * 36864 + (size_t)r * 8) = v;
}

// ---------------- low0: 3->64 fp32 conv, writes interleaved fp16 + L ------
__global__ __launch_bounds__(256)
void low0_k(const float* __restrict__ x, const float* __restrict__ w,
            const float* __restrict__ bias, _Float16* __restrict__ M,
            float* __restrict__ L)
{
    __shared__ float tile[3 * 324];
    const int tx = threadIdx.x & 15, ty = threadIdx.x >> 4;
    const int bx = blockIdx.x, by = blockIdx.y, z = blockIdx.z;
    const int ox = bx * 16 + tx, oy = by * 16 + ty;
    const int ix0 = bx * 16 - 1, iy0 = by * 16 - 1;

    for (int i = threadIdx.x; i < 3 * 324; i += 256) {
        int c = i / 324, p = i - c * 324;
        int iy = p / 18, ix = p - iy * 18;
        int gy = iy0 + iy, gx = ix0 + ix;
        float v = 0.f;
        if ((unsigned)gy < 512u && (unsigned)gx < 512u)
            v = x[(size_t)c * HW_ + (size_t)gy * 512 + gx];
        tile[i] = v;
    }
    __syncthreads();

    float p9[3][9];
    #pragma unroll
    for (int c = 0; c < 3; ++c)
        #pragma unroll
        for (int dy = 0; dy < 3; ++dy)
            #pragma unroll
            for (int dx = 0; dx < 3; ++dx)
                p9[c][dy * 3 + dx] = tile[c * 324 + (ty + dy) * 18 + tx + dx];

    float acc[16];
    #pragma unroll
    for (int o = 0; o < 16; ++o) {
        int oc = z * 16 + o;
        float a = bias[oc];
        const float* wo = w + (size_t)oc * 27;
        #pragma unroll
        for (int c = 0; c < 3; ++c)
            #pragma unroll
            for (int k = 0; k < 9; ++k)
                a = fmaf(p9[c][k], wo[c * 9 + k], a);
        acc[o] = a;
    }

    const size_t pix = (size_t)oy * 512 + ox;
    half8 h0, h1;
    #pragma unroll
    for (int o = 0; o < 8; ++o) { h0[o] = (_Float16)acc[o]; h1[o] = (_Float16)acc[8 + o]; }
    _Float16* orow = M + pix * 64 + z * 16;
    *(half8*)(orow)     = h0;
    *(half8*)(orow + 8) = h1;
    if (z == 3) {
        #pragma unroll
        for (int o = 13; o < 16; ++o)
            L[(size_t)(o - 13) * HW_ + pix] = acc[o];
    }
}

// ---------------- MFMA implicit-GEMM conv, stride 1, 512x512 --------------
// IO: fp16 channel-interleaved [pixel][64]. LDS [p][c ^ ((p&7)<<3)].
// 18 half-tap phases (s,kk); weights double-buffered in 4 KB slices via
// global_load_lds (1 chunk/thread/phase). LDS 49.7 KB -> 3 blocks/CU.
// Epilogue transposes via in_t so global stores are dense 1 KB/wave.
// DOLH: fused 3->3 tanh conv reading its stencil straight from global
// (L2-resident planes), placed after the epilogue (acc regs dead).
template<int O, int ACT, int DOLH>
__global__ __launch_bounds__(256, 4)
void conv_mfma_k(const _Float16* __restrict__ in, const _Float16* __restrict__ wt,
                 const float* __restrict__ bias, _Float16* __restrict__ out,
                 const float* __restrict__ L_in, const float* __restrict__ lhw,
                 const float* __restrict__ lhb, float* __restrict__ L_out,
                 const _Float16* __restrict__ zg)
{
    __shared__ _Float16 __attribute__((aligned(16))) in_t[2592 * 8];   // 41472 B
    __shared__ _Float16 __attribute__((aligned(16))) wbuf[2][2048];    //  8192 B
    const int tid = threadIdx.x;
    const int l = tid & 63, wv = tid >> 6;
    const int px = l & 15, g = l >> 4;
    const int bx = blockIdx.x, by = blockIdx.y;
    const int iy0 = by * 16 - 1, ix0 = bx * 16 - 1;

    // stage activations (2592 chunks) + phase-0 weight slice (256 chunks)
    #pragma unroll
    for (int k = 0; k < 11; ++k) {
        int i = tid + (k << 8);
        if (i < 2592) {
            int p = i >> 3, jl = i & 7;
            int iy = p / 18, ix = p - iy * 18;
            int gy = iy0 + iy, gx = ix0 + ix;
            int j = jl ^ (p & 7);
            const _Float16* src = ((unsigned)gy < 512u && (unsigned)gx < 512u)
                ? in + ((size_t)gy * 512 + gx) * 64 + j * 8 : zg;
            __builtin_amdgcn_global_load_lds(
                (const __attribute__((address_space(1))) void*)src,
                (__attribute__((address_space(3))) void*)(in_t + (size_t)(i - l) * 8),
                16, 0, 0);
        }
    }
    __builtin_amdgcn_global_load_lds(
        (const __attribute__((address_space(1))) void*)(wt + tid * 8),
        (__attribute__((address_space(3))) void*)(wbuf[0] + (size_t)(tid - l) * 8),
        16, 0, 0);
    __syncthreads();

    f32x4 acc[4][4];
    #pragma unroll
    for (int m = 0; m < 4; ++m)
        #pragma unroll
        for (int f = 0; f < 4; ++f) acc[m][f] = (f32x4){0.f, 0.f, 0.f, 0.f};

    #pragma unroll
    for (int ph = 0; ph < 18; ++ph) {
        if (ph < 17) {
            __builtin_amdgcn_global_load_lds(
                (const __attribute__((address_space(1))) void*)(wt + ((ph + 1) << 11) + tid * 8),
                (__attribute__((address_space(3))) void*)(wbuf[(ph + 1) & 1] + (size_t)(tid - l) * 8),
                16, 0, 0);
        }
        const int s = ph >> 1, kk = ph & 1;
        const int dy = s / 3, dx = s - dy * 3;
        const _Float16* wb = wbuf[ph & 1];
        half8 a[4];
        #pragma unroll
        for (int m = 0; m < 4; ++m)
            a[m] = *(const half8*)(wb + (m << 9) + l * 8);
        #pragma unroll
        for (int f = 0; f < 4; ++f) {
            int ipix = (4 * wv + f + dy) * 18 + px + dx;
            int rb = ipix * 64, sw = (ipix & 7) << 3;
            half8 b = *(const half8*)&in_t[rb + ((kk * 32 + g * 8) ^ sw)];
            #pragma unroll
            for (int m = 0; m < 4; ++m)
                acc[m][f] = __builtin_amdgcn_mfma_f32_16x16x32_f16(
                    a[m], b, acc[m][f], 0, 0, 0);
        }
        __syncthreads();   // wbuf[ph&1] free; wbuf[(ph+1)&1] landed (vmcnt drain)
    }

    float bs[4][4];
    #pragma unroll
    for (int m = 0; m < 4; ++m)
        #pragma unroll
        for (int r = 0; r < 4; ++r) {
            int o = m * 16 + g * 4 + r;
            bs[m][r] = (o < O) ? bias[o] : 0.f;
        }

    // ---- epilogue: transpose via LDS (reuse in_t) -> dense 1KB stores ----
    #pragma unroll
    for (int f = 0; f < 4; ++f) {
        const int p = (4 * wv + f) * 16 + px;
        const int sw = p & 7;
        #pragma unroll
        for (int m = 0; m < 4; ++m) {
            union { _Float16 h[4]; uint2 u; } pk;
            #pragma unroll
            for (int r = 0; r < 4; ++r) {
                int o = m * 16 + g * 4 + r;
                float v = acc[m][f][r] + bs[m][r];
                if (ACT) v = fmaxf(v, 0.f);
                pk.h[r] = (o < O) ? (_Float16)v : (_Float16)0.f;
            }
            int chunk = (m * 2 + (g >> 1)) ^ sw;
            *(uint2*)&in_t[p * 64 + chunk * 8 + (g & 1) * 4] = pk.u;
        }
    }
    __syncthreads();
    // pixel-linear read-back; wave stores are contiguous 1 KB.
    #pragma unroll
    for (int k = 0; k < 8; ++k) {
        int q = (k << 8) + tid;           // chunk id 0..2047
        int p = q >> 3, jc = q & 7;
        half8 v = *(const half8*)&in_t[p * 64 + ((jc ^ (p & 7)) * 8)];
        int row = p >> 4, col = p & 15;
        _Float16* dst = out + (((size_t)(by * 16 + row) * 512) + bx * 16 + col) * 64 + jc * 8;
        *(half8*)dst = v;
    }

    // fused lh: 3->3 fp32 conv + tanh (exact path), stencil from global
    if (DOLH) {
        const int tx = tid & 15, ty = tid >> 4;
        const int oy = by * 16 + ty, ox = bx * 16 + tx;
        float pv[27];
        #pragma unroll
        for (int c = 0; c < 3; ++c)
            #pragma unroll
            for (int d2 = 0; d2 < 9; ++d2) {
                int gy = oy + d2 / 3 - 1, gx = ox + d2 % 3 - 1;
                pv[c * 9 + d2] = ((unsigned)gy < 512u && (unsigned)gx < 512u)
                    ? L_in[(size_t)c * HW_ + (size_t)gy * 512 + gx] : 0.f;
            }
        const size_t pix = (size_t)oy * 512 + ox;
        #pragma unroll
        for (int oc = 0; oc < 3; ++oc) {
            float a = lhb[oc];
            #pragma unroll
            for (int k = 0; k < 27; ++k)
                a = fmaf(pv[k], lhw[oc * 27 + k], a);
            L_out[(size_t)oc * HW_ + pix] = tanhf(a);
        }
    }
}

// ---------------- MFMA stride-2 conv + relu + fused 2x2 maxpool -----------
// Same 18-phase kk-split weight staging. LDS 45.2 KB -> 3 blocks/CU.
template<int FP32OUT>
__global__ __launch_bounds__(256, 4)
void conv_s2_pool_k(const _Float16* __restrict__ in, int Hin,
                    const _Float16* __restrict__ wt,
                    const float* __restrict__ bias, void* __restrict__ outv,
                    const _Float16* __restrict__ zg)
{
    const int Hp = Hin >> 2;
    __shared__ _Float16 __attribute__((aligned(16))) in_t[2312 * 8];   // 36992 B
    __shared__ _Float16 __attribute__((aligned(16))) wbuf[2][2048];    //  8192 B
    const int tid = threadIdx.x;
    const int l = tid & 63, wv = tid >> 6;
    const int n = l & 15, g = l >> 4;
    const int bx = blockIdx.x, by = blockIdx.y;
    const int iy0 = by * 16 - 1, ix0 = bx * 16 - 1;

    #pragma unroll
    for (int k = 0; k < 10; ++k) {
        int i = tid + (k << 8);
        if (i < 2312) {
            int p = i >> 3, jl = i & 7;
            int iy = p / 17, ix = p - iy * 17;
            int gy = iy0 + iy, gx = ix0 + ix;
            int j = jl ^ (p & 7);
            const _Float16* src =
                ((unsigned)gy < (unsigned)Hin && (unsigned)gx < (unsigned)Hin)
                    ? in + ((size_t)gy * Hin + gx) * 64 + j * 8 : zg;
            __builtin_amdgcn_global_load_lds(
                (const __attribute__((address_space(1))) void*)src,
                (__attribute__((address_space(3))) void*)(in_t + (size_t)(i - l) * 8),
                16, 0, 0);
        }
    }
    __builtin_amdgcn_global_load_lds(
        (const __attribute__((address_space(1))) void*)(wt + tid * 8),
        (__attribute__((address_space(3))) void*)(wbuf[0] + (size_t)(tid - l) * 8),
        16, 0, 0);
    __syncthreads();

    f32x4 acc[4];
    #pragma unroll
    for (int f = 0; f < 4; ++f) acc[f] = (f32x4){0.f, 0.f, 0.f, 0.f};

    const int py_lo = n >> 3, pxc = n & 7;
    #pragma unroll
    for (int ph = 0; ph < 18; ++ph) {
        if (ph < 17) {
            __builtin_amdgcn_global_load_lds(
                (const __attribute__((address_space(1))) void*)(wt + ((ph + 1) << 11) + tid * 8),
                (__attribute__((address_space(3))) void*)(wbuf[(ph + 1) & 1] + (size_t)(tid - l) * 8),
                16, 0, 0);
        }
        const int s = ph >> 1, kk = ph & 1;
        const int dy = s / 3, dx = s - dy * 3;
        half8 a = *(const half8*)(wbuf[ph & 1] + (wv << 9) + l * 8);
        #pragma unroll
        for (int f = 0; f < 4; ++f) {
            int py = 2 * f + py_lo;
            int ipix = (2 * py + dy) * 17 + 2 * pxc + dx;
            int rb = ipix * 64, sw = (ipix & 7) << 3;
            half8 b = *(const half8*)&in_t[rb + ((kk * 32 + g * 8) ^ sw)];
            acc[f] = __builtin_amdgcn_mfma_f32_16x16x32_f16(a, b, acc[f], 0, 0, 0);
        }
        __syncthreads();
    }

    float bs[4];
    #pragma unroll
    for (int r = 0; r < 4; ++r) bs[r] = bias[wv * 16 + g * 4 + r];

    #pragma unroll
    for (int f = 0; f < 4; ++f)
        #pragma unroll
        for (int r = 0; r < 4; ++r) {
            float v = fmaxf(acc[f][r] + bs[r], 0.f);
            v = fmaxf(v, __shfl_xor(v, 1));
            v = fmaxf(v, __shfl_xor(v, 8));
            if ((l & 9) == 0) {
                int o = wv * 16 + g * 4 + r;
                size_t pp = ((size_t)(by * 4 + f) * Hp + bx * 4 + (n >> 1)) * 64 + o;
                if (FP32OUT) ((float*)outv)[pp] = v;
                else         ((_Float16*)outv)[pp] = (_Float16)v;
            }
        }
}

// ---------------- tail ----------------------------------------------------
__global__ void meanlin_k(const float* __restrict__ h,   // [64pix][64ch] f32
                          const float* __restrict__ lw,
                          const float* __restrict__ lb,
                          float* __restrict__ wm)
{
    __shared__ float g[64];
    int t = threadIdx.x;
    if (t < 64) {
        float s = 0.f;
        for (int p = 0; p < 64; ++p) s += h[p * 64 + t];
        g[t] = s * (1.f / 64.f);
    }
    __syncthreads();
    if (t < 30) {
        float s = lb[t];
        for (int c = 0; c < 64; ++c) s = fmaf(g[c], lw[t * 64 + c], s);
        wm[t] = s;
    }
}

__global__ __launch_bounds__(256)
void final_k(const float* __restrict__ I3, const float* __restrict__ wm,
             float* __restrict__ out)
{
    __shared__ float W[30];
    if (threadIdx.x < 30) W[threadIdx.x] = wm[threadIdx.x];
    __syncthreads();
    const int HW = 512 * 512;
    for (int i = blockIdx.x * blockDim.x + threadIdx.x; i < HW;
         i += gridDim.x * blockDim.x) {
        float r = I3[i], g = I3[HW + i], b = I3[2 * HW + i];
        float f[10] = { r * r, r * g, r * b, r, g * g, g * b, g, b * b, b, 1.f };
        #pragma unroll
        for (int o = 0; o < 3; ++o) {
            float s = 0.f;
            #pragma unroll
            for (int k = 0; k < 10; ++k) s = fmaf(W[o * 10 + k], f[k], s);
            out[(size_t)o * HW + i] = s;
        }
    }
}

extern "C" void kernel_launch(void* const* d_in, const int* in_sizes, int n_in,
                              void* d_out, int out_size, void* d_ws, size_t ws_size,
                              hipStream_t stream)
{
    const float* x      = (const float*)d_in[0];
    const float* low0_w = (const float*)d_in[1];
    const float* low0_b = (const float*)d_in[2];
    const float* rh_w   = (const float*)d_in[3];
    const float* rh_b   = (const float*)d_in[4];
    const float* lh_w   = (const float*)d_in[5];
    const float* lh_b   = (const float*)d_in[6];
    const float* hl0_w  = (const float*)d_in[7];
    const float* hl0_b  = (const float*)d_in[8];
    const float* hl_w   = (const float*)d_in[9];
    const float* hl_b   = (const float*)d_in[10];
    const float* lin_w  = (const float*)d_in[11];
    const float* lin_b  = (const float*)d_in[12];
    float* out = (float*)d_out;

    const size_t HW = 512 * 512;
    _Float16* M0 = (_Float16*)d_ws;                       // [HW][64]
    _Float16* M1 = M0 + (size_t)64 * HW;
    _Float16* P0 = M1 + (size_t)64 * HW;                  // [16384][64]
    _Float16* P1 = P0 + (size_t)16384 * 64;               // [1024][64]
    _Float16* WT = P1 + (size_t)1024 * 64;                // 8*36864
    _Float16* ZG = WT + (size_t)8 * 36864;                // 32-half zero guard
    float*    P2 = (float*)(ZG + 32);                     // [64][64] f32
    float*    L0 = P2 + 64 * 64;                          // 3 fp32 planes
    float*    L1 = L0 + (size_t)3 * HW;
    float*    WM = L1 + (size_t)3 * HW;                   // 30 (pad 32)

    dim3 blk(256);
    dim3 g512(32, 32, 1);

    wtrans_k<<<dim3(144), blk, 0, stream>>>(rh_w, hl0_w, hl_w, WT, ZG);

    // I = conv(x): fp16 interleaved M0 + exact fp32 ch61..63 -> L0
    low0_k<<<dim3(32, 32, 4), blk, 0, stream>>>(x, low0_w, low0_b, M0, L0);

    _Float16* cur = M0; _Float16* nxt = M1;
    float* Lc = L0; float* Ln = L1;
    for (int i = 0; i < 4; ++i) {
        conv_mfma_k<61, 1, 1><<<g512, blk, 0, stream>>>(
            cur, WT + (size_t)i * 36864, rh_b + i * 61, nxt,
            Lc, lh_w + (size_t)i * 81, lh_b + i * 3, Ln, ZG);
        _Float16* t = cur; cur = nxt; nxt = t;
        float* tl = Lc; Lc = Ln; Ln = tl;
    }

    // h = conv(I[:, :61]) -> 64ch fp16 interleaved
    conv_mfma_k<64, 0, 0><<<g512, blk, 0, stream>>>(
        cur, WT + (size_t)4 * 36864, hl0_b, nxt,
        nullptr, nullptr, nullptr, nullptr, ZG);

    conv_s2_pool_k<0><<<dim3(32, 32), blk, 0, stream>>>(
        nxt, 512, WT + (size_t)5 * 36864, hl_b, (void*)P0, ZG);
    conv_s2_pool_k<0><<<dim3(8, 8), blk, 0, stream>>>(
        P0, 128, WT + (size_t)6 * 36864, hl_b + 64, (void*)P1, ZG);
    conv_s2_pool_k<1><<<dim3(2, 2), blk, 0, stream>>>(
        P1, 32, WT + (size_t)7 * 36864, hl_b + 128, (void*)P2, ZG);

    meanlin_k<<<dim3(1), dim3(64), 0, stream>>>(P2, lin_w, lin_b, WM);

    final_k<<<dim3(2048), blk, 0, stream>>>(Lc, WM, out);
}

// Round 9
// 217.541 us; speedup vs baseline: 1.1550x; 1.1550x over previous
//
#include <hip/hip_runtime.h>
#include <cstdint>

typedef _Float16 half8 __attribute__((ext_vector_type(8)));
typedef float f32x4 __attribute__((ext_vector_type(4)));

#define HW_ (512*512)

// ---------------- weight transform: fp32 -> frag-linear fp16 --------------
// 8 layers: 0-3 rh (O=61,CIN=61), 4 hl0 (O=64,CIN=61), 5-7 hl (O=64,CIN=64).
// Per layer 36864 halfs: chunk ci = s*8 + kk*4 + m, 512 halfs per chunk.
// Element (lane,j): A[o = m*16 + (lane&15)][c = kk*32 + (lane>>4)*8 + j].
// Tap slice s = 4096 contiguous halfs (chunks s*8..s*8+7).
// Block 0 also zeroes the 32-half guard region ZG (OOB staging target).
__global__ __launch_bounds__(256) void wtrans_k(
    const float* __restrict__ rh_w, const float* __restrict__ hl0_w,
    const float* __restrict__ hl_w, _Float16* __restrict__ wt,
    _Float16* __restrict__ zg)
{
    if (blockIdx.x == 0 && threadIdx.x < 32) zg[threadIdx.x] = (_Float16)0.f;
    int t = blockIdx.x * 256 + threadIdx.x;
    if (t >= 8 * 4608) return;
    int layer = t / 4608;
    int r = t - layer * 4608;
    int lane = r & 63, ci = r >> 6;
    int m = ci & 3, kk = (ci >> 2) & 1, s = ci >> 3;
    int o = m * 16 + (lane & 15);
    int cb = kk * 32 + ((lane >> 4) & 3) * 8;
    const float* w; int O, CIN;
    if (layer < 4)      { w = rh_w + (size_t)layer * 61 * 61 * 9; O = 61; CIN = 61; }
    else if (layer == 4){ w = hl0_w;                              O = 64; CIN = 61; }
    else                { w = hl_w + (size_t)(layer - 5) * 64 * 64 * 9; O = 64; CIN = 64; }
    half8 v;
    #pragma unroll
    for (int j = 0; j < 8; ++j) {
        int c = cb + j;
        float f = (o < O && c < CIN) ? w[((size_t)o * CIN + c) * 9 + s] : 0.f;
        v[j] = (_Float16)f;
    }
    *(half8*)(wt + (size_t)layer * 36864 + (size_t)r * 8) = v;
}

// ---------------- low0: 3->64 fp32 conv, writes interleaved fp16 + L ------
__global__ __launch_bounds__(256)
void low0_k(const float* __restrict__ x, const float* __restrict__ w,
            const float* __restrict__ bias, _Float16* __restrict__ M,
            float* __restrict__ L)
{
    __shared__ float tile[3 * 324];
    const int tx = threadIdx.x & 15, ty = threadIdx.x >> 4;
    const int bx = blockIdx.x, by = blockIdx.y, z = blockIdx.z;
    const int ox = bx * 16 + tx, oy = by * 16 + ty;
    const int ix0 = bx * 16 - 1, iy0 = by * 16 - 1;

    for (int i = threadIdx.x; i < 3 * 324; i += 256) {
        int c = i / 324, p = i - c * 324;
        int iy = p / 18, ix = p - iy * 18;
        int gy = iy0 + iy, gx = ix0 + ix;
        float v = 0.f;
        if ((unsigned)gy < 512u && (unsigned)gx < 512u)
            v = x[(size_t)c * HW_ + (size_t)gy * 512 + gx];
        tile[i] = v;
    }
    __syncthreads();

    float p9[3][9];
    #pragma unroll
    for (int c = 0; c < 3; ++c)
        #pragma unroll
        for (int dy = 0; dy < 3; ++dy)
            #pragma unroll
            for (int dx = 0; dx < 3; ++dx)
                p9[c][dy * 3 + dx] = tile[c * 324 + (ty + dy) * 18 + tx + dx];

    float acc[16];
    #pragma unroll
    for (int o = 0; o < 16; ++o) {
        int oc = z * 16 + o;
        float a = bias[oc];
        const float* wo = w + (size_t)oc * 27;
        #pragma unroll
        for (int c = 0; c < 3; ++c)
            #pragma unroll
            for (int k = 0; k < 9; ++k)
                a = fmaf(p9[c][k], wo[c * 9 + k], a);
        acc[o] = a;
    }

    const size_t pix = (size_t)oy * 512 + ox;
    half8 h0, h1;
    #pragma unroll
    for (int o = 0; o < 8; ++o) { h0[o] = (_Float16)acc[o]; h1[o] = (_Float16)acc[8 + o]; }
    _Float16* orow = M + pix * 64 + z * 16;
    *(half8*)(orow)     = h0;
    *(half8*)(orow + 8) = h1;
    if (z == 3) {
        #pragma unroll
        for (int o = 13; o < 16; ++o)
            L[(size_t)(o - 13) * HW_ + pix] = acc[o];
    }
}

// ---------------- MFMA implicit-GEMM conv, stride 1, 512x512 --------------
// IO: fp16 channel-interleaved [pixel][64]. LDS [p][c ^ ((p&7)<<3)].
// Activations staged via global_load_lds width=16; weights staged PER TAP
// (8 KB slice, double-buffered) into LDS, read as A-frags by all 4 waves.
// 1-D grid of 1024 with bijective XCD chunk swizzle: each XCD owns a
// contiguous 4-row y-band so vertical halo overlap hits the local L2.
// Epilogue transposes via in_t so global stores are dense 1 KB/wave.
// DOLH: fused 3->3 tanh conv from global (L2-resident), after epilogue.
template<int O, int ACT, int DOLH>
__global__ __launch_bounds__(256, 2)
void conv_mfma_k(const _Float16* __restrict__ in, const _Float16* __restrict__ wt,
                 const float* __restrict__ bias, _Float16* __restrict__ out,
                 const float* __restrict__ L_in, const float* __restrict__ lhw,
                 const float* __restrict__ lhb, float* __restrict__ L_out,
                 const _Float16* __restrict__ zg)
{
    __shared__ _Float16 __attribute__((aligned(16))) in_t[2592 * 8];   // 41472 B
    __shared__ _Float16 __attribute__((aligned(16))) wbuf[2][4096];    // 16384 B
    const int tid = threadIdx.x;
    const int l = tid & 63, wv = tid >> 6;
    const int px = l & 15, g = l >> 4;
    const int orig = blockIdx.x;
    const int id = ((orig & 7) << 7) + (orig >> 3);    // XCD chunk swizzle
    const int bx = id & 31, by = id >> 5;
    const int iy0 = by * 16 - 1, ix0 = bx * 16 - 1;

    // stage activations (2592 chunks) + tap-0 weights (512 chunks)
    #pragma unroll
    for (int k = 0; k < 11; ++k) {
        int i = tid + (k << 8);
        if (i < 2592) {
            int p = i >> 3, jl = i & 7;
            int iy = p / 18, ix = p - iy * 18;
            int gy = iy0 + iy, gx = ix0 + ix;
            int j = jl ^ (p & 7);
            const _Float16* src = ((unsigned)gy < 512u && (unsigned)gx < 512u)
                ? in + ((size_t)gy * 512 + gx) * 64 + j * 8 : zg;
            __builtin_amdgcn_global_load_lds(
                (const __attribute__((address_space(1))) void*)src,
                (__attribute__((address_space(3))) void*)(in_t + (size_t)(i - l) * 8),
                16, 0, 0);
        }
    }
    #pragma unroll
    for (int it = 0; it < 2; ++it) {
        int ci = (it << 8) + tid;
        __builtin_amdgcn_global_load_lds(
            (const __attribute__((address_space(1))) void*)(wt + ci * 8),
            (__attribute__((address_space(3))) void*)(wbuf[0] + (size_t)(ci - l) * 8),
            16, 0, 0);
    }
    __syncthreads();

    float bs[4][4];
    #pragma unroll
    for (int m = 0; m < 4; ++m)
        #pragma unroll
        for (int r = 0; r < 4; ++r) {
            int o = m * 16 + g * 4 + r;
            bs[m][r] = (o < O) ? bias[o] : 0.f;
        }

    f32x4 acc[4][4];
    #pragma unroll
    for (int m = 0; m < 4; ++m)
        #pragma unroll
        for (int f = 0; f < 4; ++f) acc[m][f] = (f32x4){0.f, 0.f, 0.f, 0.f};

    #pragma unroll
    for (int s = 0; s < 9; ++s) {
        // issue next tap's weight slice (lands before next barrier)
        if (s < 8) {
            #pragma unroll
            for (int it = 0; it < 2; ++it) {
                int ci = (it << 8) + tid;
                __builtin_amdgcn_global_load_lds(
                    (const __attribute__((address_space(1))) void*)(wt + ((s + 1) << 12) + ci * 8),
                    (__attribute__((address_space(3))) void*)(wbuf[(s + 1) & 1] + (size_t)(ci - l) * 8),
                    16, 0, 0);
            }
        }
        const _Float16* wb = wbuf[s & 1];
        half8 a[8];
        #pragma unroll
        for (int q = 0; q < 8; ++q)
            a[q] = *(const half8*)(wb + (q << 9) + l * 8);

        const int dy = s / 3, dx = s - dy * 3;
        #pragma unroll
        for (int f = 0; f < 4; ++f) {
            int ipix = (4 * wv + f + dy) * 18 + px + dx;
            int rb = ipix * 64, sw = (ipix & 7) << 3;
            #pragma unroll
            for (int kk = 0; kk < 2; ++kk) {
                half8 b = *(const half8*)&in_t[rb + ((kk * 32 + g * 8) ^ sw)];
                #pragma unroll
                for (int m = 0; m < 4; ++m)
                    acc[m][f] = __builtin_amdgcn_mfma_f32_16x16x32_f16(
                        a[kk * 4 + m], b, acc[m][f], 0, 0, 0);
            }
        }
        __syncthreads();   // wbuf[s&1] free; wbuf[(s+1)&1] landed (vmcnt drain)
    }

    // ---- epilogue: transpose via LDS (reuse in_t) -> dense 1KB stores ----
    #pragma unroll
    for (int f = 0; f < 4; ++f) {
        const int p = (4 * wv + f) * 16 + px;
        const int sw = p & 7;
        #pragma unroll
        for (int m = 0; m < 4; ++m) {
            union { _Float16 h[4]; uint2 u; } pk;
            #pragma unroll
            for (int r = 0; r < 4; ++r) {
                int o = m * 16 + g * 4 + r;
                float v = acc[m][f][r] + bs[m][r];
                if (ACT) v = fmaxf(v, 0.f);
                pk.h[r] = (o < O) ? (_Float16)v : (_Float16)0.f;
            }
            int chunk = (m * 2 + (g >> 1)) ^ sw;
            *(uint2*)&in_t[p * 64 + chunk * 8 + (g & 1) * 4] = pk.u;
        }
    }
    __syncthreads();
    // pixel-linear read-back; wave stores are contiguous 1 KB.
    #pragma unroll
    for (int k = 0; k < 8; ++k) {
        int q = (k << 8) + tid;           // chunk id 0..2047
        int p = q >> 3, jc = q & 7;
        half8 v = *(const half8*)&in_t[p * 64 + ((jc ^ (p & 7)) * 8)];
        int row = p >> 4, col = p & 15;
        _Float16* dst = out + (((size_t)(by * 16 + row) * 512) + bx * 16 + col) * 64 + jc * 8;
        *(half8*)dst = v;
    }

    // fused lh: 3->3 fp32 conv + tanh (exact path), stencil from global
    if (DOLH) {
        const int tx = tid & 15, ty = tid >> 4;
        const int oy = by * 16 + ty, ox = bx * 16 + tx;
        float pv[27];
        #pragma unroll
        for (int c = 0; c < 3; ++c)
            #pragma unroll
            for (int d2 = 0; d2 < 9; ++d2) {
                int gy = oy + d2 / 3 - 1, gx = ox + d2 % 3 - 1;
                pv[c * 9 + d2] = ((unsigned)gy < 512u && (unsigned)gx < 512u)
                    ? L_in[(size_t)c * HW_ + (size_t)gy * 512 + gx] : 0.f;
            }
        const size_t pix = (size_t)oy * 512 + ox;
        #pragma unroll
        for (int oc = 0; oc < 3; ++oc) {
            float a = lhb[oc];
            #pragma unroll
            for (int k = 0; k < 27; ++k)
                a = fmaf(pv[k], lhw[oc * 27 + k], a);
            L_out[(size_t)oc * HW_ + pix] = tanhf(a);
        }
    }
}

// ---------------- MFMA stride-2 conv + relu + fused 2x2 maxpool -----------
// Same per-tap LDS weight staging. NB = blocks per side (1-D grid NB*NB);
// XCD swizzle applied only at NB=32 (1024 blocks, divisible by 8).
template<int FP32OUT, int NB>
__global__ __launch_bounds__(256, 3)
void conv_s2_pool_k(const _Float16* __restrict__ in, int Hin,
                    const _Float16* __restrict__ wt,
                    const float* __restrict__ bias, void* __restrict__ outv,
                    const _Float16* __restrict__ zg)
{
    const int Hp = Hin >> 2;
    __shared__ _Float16 __attribute__((aligned(16))) in_t[2312 * 8];   // 36992 B
    __shared__ _Float16 __attribute__((aligned(16))) wbuf[2][4096];    // 16384 B
    const int tid = threadIdx.x;
    const int l = tid & 63, wv = tid >> 6;
    const int n = l & 15, g = l >> 4;
    int id = blockIdx.x;
    if (NB == 32) id = ((id & 7) << 7) + (id >> 3);    // XCD chunk swizzle
    const int bx = id % NB, by = id / NB;
    const int iy0 = by * 16 - 1, ix0 = bx * 16 - 1;

    #pragma unroll
    for (int k = 0; k < 10; ++k) {
        int i = tid + (k << 8);
        if (i < 2312) {
            int p = i >> 3, jl = i & 7;
            int iy = p / 17, ix = p - iy * 17;
            int gy = iy0 + iy, gx = ix0 + ix;
            int j = jl ^ (p & 7);
            const _Float16* src =
                ((unsigned)gy < (unsigned)Hin && (unsigned)gx < (unsigned)Hin)
                    ? in + ((size_t)gy * Hin + gx) * 64 + j * 8 : zg;
            __builtin_amdgcn_global_load_lds(
                (const __attribute__((address_space(1))) void*)src,
                (__attribute__((address_space(3))) void*)(in_t + (size_t)(i - l) * 8),
                16, 0, 0);
        }
    }
    #pragma unroll
    for (int it = 0; it < 2; ++it) {
        int ci = (it << 8) + tid;
        __builtin_amdgcn_global_load_lds(
            (const __attribute__((address_space(1))) void*)(wt + ci * 8),
            (__attribute__((address_space(3))) void*)(wbuf[0] + (size_t)(ci - l) * 8),
            16, 0, 0);
    }
    __syncthreads();

    float bs[4];
    #pragma unroll
    for (int r = 0; r < 4; ++r) bs[r] = bias[wv * 16 + g * 4 + r];

    f32x4 acc[4];
    #pragma unroll
    for (int f = 0; f < 4; ++f) acc[f] = (f32x4){0.f, 0.f, 0.f, 0.f};

    const int py_lo = n >> 3, pxc = n & 7;
    #pragma unroll
    for (int s = 0; s < 9; ++s) {
        if (s < 8) {
            #pragma unroll
            for (int it = 0; it < 2; ++it) {
                int ci = (it << 8) + tid;
                __builtin_amdgcn_global_load_lds(
                    (const __attribute__((address_space(1))) void*)(wt + ((s + 1) << 12) + ci * 8),
                    (__attribute__((address_space(3))) void*)(wbuf[(s + 1) & 1] + (size_t)(ci - l) * 8),
                    16, 0, 0);
            }
        }
        const _Float16* wb = wbuf[s & 1];
        half8 a[2];
        #pragma unroll
        for (int kk = 0; kk < 2; ++kk)
            a[kk] = *(const half8*)(wb + ((kk * 4 + wv) << 9) + l * 8);

        const int dy = s / 3, dx = s - dy * 3;
        #pragma unroll
        for (int f = 0; f < 4; ++f) {
            int py = 2 * f + py_lo;
            int ipix = (2 * py + dy) * 17 + 2 * pxc + dx;
            int rb = ipix * 64, sw = (ipix & 7) << 3;
            #pragma unroll
            for (int kk = 0; kk < 2; ++kk) {
                half8 b = *(const half8*)&in_t[rb + ((kk * 32 + g * 8) ^ sw)];
                acc[f] = __builtin_amdgcn_mfma_f32_16x16x32_f16(a[kk], b, acc[f], 0, 0, 0);
            }
        }
        __syncthreads();
    }

    #pragma unroll
    for (int f = 0; f < 4; ++f)
        #pragma unroll
        for (int r = 0; r < 4; ++r) {
            float v = fmaxf(acc[f][r] + bs[r], 0.f);
            v = fmaxf(v, __shfl_xor(v, 1));
            v = fmaxf(v, __shfl_xor(v, 8));
            if ((l & 9) == 0) {
                int o = wv * 16 + g * 4 + r;
                size_t pp = ((size_t)(by * 4 + f) * Hp + bx * 4 + (n >> 1)) * 64 + o;
                if (FP32OUT) ((float*)outv)[pp] = v;
                else         ((_Float16*)outv)[pp] = (_Float16)v;
            }
        }
}

// ---------------- tail ----------------------------------------------------
__global__ void meanlin_k(const float* __restrict__ h,   // [64pix][64ch] f32
                          const float* __restrict__ lw,
                          const float* __restrict__ lb,
                          float* __restrict__ wm)
{
    __shared__ float g[64];
    int t = threadIdx.x;
    if (t < 64) {
        float s = 0.f;
        for (int p = 0; p < 64; ++p) s += h[p * 64 + t];
        g[t] = s * (1.f / 64.f);
    }
    __syncthreads();
    if (t < 30) {
        float s = lb[t];
        for (int c = 0; c < 64; ++c) s = fmaf(g[c], lw[t * 64 + c], s);
        wm[t] = s;
    }
}

__global__ __launch_bounds__(256)
void final_k(const float* __restrict__ I3, const float* __restrict__ wm,
             float* __restrict__ out)
{
    __shared__ float W[30];
    if (threadIdx.x < 30) W[threadIdx.x] = wm[threadIdx.x];
    __syncthreads();
    const int HW = 512 * 512;
    for (int i = blockIdx.x * blockDim.x + threadIdx.x; i < HW;
         i += gridDim.x * blockDim.x) {
        float r = I3[i], g = I3[HW + i], b = I3[2 * HW + i];
        float f[10] = { r * r, r * g, r * b, r, g * g, g * b, g, b * b, b, 1.f };
        #pragma unroll
        for (int o = 0; o < 3; ++o) {
            float s = 0.f;
            #pragma unroll
            for (int k = 0; k < 10; ++k) s = fmaf(W[o * 10 + k], f[k], s);
            out[(size_t)o * HW + i] = s;
        }
    }
}

extern "C" void kernel_launch(void* const* d_in, const int* in_sizes, int n_in,
                              void* d_out, int out_size, void* d_ws, size_t ws_size,
                              hipStream_t stream)
{
    const float* x      = (const float*)d_in[0];
    const float* low0_w = (const float*)d_in[1];
    const float* low0_b = (const float*)d_in[2];
    const float* rh_w   = (const float*)d_in[3];
    const float* rh_b   = (const float*)d_in[4];
    const float* lh_w   = (const float*)d_in[5];
    const float* lh_b   = (const float*)d_in[6];
    const float* hl0_w  = (const float*)d_in[7];
    const float* hl0_b  = (const float*)d_in[8];
    const float* hl_w   = (const float*)d_in[9];
    const float* hl_b   = (const float*)d_in[10];
    const float* lin_w  = (const float*)d_in[11];
    const float* lin_b  = (const float*)d_in[12];
    float* out = (float*)d_out;

    const size_t HW = 512 * 512;
    _Float16* M0 = (_Float16*)d_ws;                       // [HW][64]
    _Float16* M1 = M0 + (size_t)64 * HW;
    _Float16* P0 = M1 + (size_t)64 * HW;                  // [16384][64]
    _Float16* P1 = P0 + (size_t)16384 * 64;               // [1024][64]
    _Float16* WT = P1 + (size_t)1024 * 64;                // 8*36864
    _Float16* ZG = WT + (size_t)8 * 36864;                // 32-half zero guard
    float*    P2 = (float*)(ZG + 32);                     // [64][64] f32
    float*    L0 = P2 + 64 * 64;                          // 3 fp32 planes
    float*    L1 = L0 + (size_t)3 * HW;
    float*    WM = L1 + (size_t)3 * HW;                   // 30 (pad 32)

    dim3 blk(256);

    wtrans_k<<<dim3(144), blk, 0, stream>>>(rh_w, hl0_w, hl_w, WT, ZG);

    // I = conv(x): fp16 interleaved M0 + exact fp32 ch61..63 -> L0
    low0_k<<<dim3(32, 32, 4), blk, 0, stream>>>(x, low0_w, low0_b, M0, L0);

    _Float16* cur = M0; _Float16* nxt = M1;
    float* Lc = L0; float* Ln = L1;
    for (int i = 0; i < 4; ++i) {
        conv_mfma_k<61, 1, 1><<<dim3(1024), blk, 0, stream>>>(
            cur, WT + (size_t)i * 36864, rh_b + i * 61, nxt,
            Lc, lh_w + (size_t)i * 81, lh_b + i * 3, Ln, ZG);
        _Float16* t = cur; cur = nxt; nxt = t;
        float* tl = Lc; Lc = Ln; Ln = tl;
    }

    // h = conv(I[:, :61]) -> 64ch fp16 interleaved
    conv_mfma_k<64, 0, 0><<<dim3(1024), blk, 0, stream>>>(
        cur, WT + (size_t)4 * 36864, hl0_b, nxt,
        nullptr, nullptr, nullptr, nullptr, ZG);

    conv_s2_pool_k<0, 32><<<dim3(1024), blk, 0, stream>>>(
        nxt, 512, WT + (size_t)5 * 36864, hl_b, (void*)P0, ZG);
    conv_s2_pool_k<0, 8><<<dim3(64), blk, 0, stream>>>(
        P0, 128, WT + (size_t)6 * 36864, hl_b + 64, (void*)P1, ZG);
    conv_s2_pool_k<1, 2><<<dim3(4), blk, 0, stream>>>(
        P1, 32, WT + (size_t)7 * 36864, hl_b + 128, (void*)P2, ZG);

    meanlin_k<<<dim3(1), dim3(64), 0, stream>>>(P2, lin_w, lin_b, WM);

    final_k<<<dim3(2048), blk, 0, stream>>>(Lc, WM, out);
}

// Round 10
// 208.516 us; speedup vs baseline: 1.2050x; 1.0433x over previous
//
#include <hip/hip_runtime.h>
#include <cstdint>

typedef _Float16 half8 __attribute__((ext_vector_type(8)));
typedef float f32x4 __attribute__((ext_vector_type(4)));

#define HW_ (512*512)

// ---------------- pre: weight transform + low0 in one grid ----------------
// Blocks 0..143: wtrans (fp32 -> frag-linear fp16, 8 layers; layout per
// layer: chunk ci = s*8 + kk*4 + m, 512 halfs/chunk, element (lane,j):
// A[o=m*16+(lane&15)][c=kk*32+(lane>>4)*8+j]; tap slice s = 4096 halfs).
// Block 0 zeroes the 32-half guard ZG. Blocks 144..4239: low0 3->64 conv,
// fp16 interleaved M + exact fp32 ch61..63 planes -> L.
__global__ __launch_bounds__(256)
void pre_k(const float* __restrict__ x, const float* __restrict__ low0_w,
           const float* __restrict__ low0_b,
           const float* __restrict__ rh_w, const float* __restrict__ hl0_w,
           const float* __restrict__ hl_w, _Float16* __restrict__ M,
           float* __restrict__ L, _Float16* __restrict__ wt,
           _Float16* __restrict__ zg)
{
    __shared__ float tile[3 * 324];
    if (blockIdx.x < 144) {
        if (blockIdx.x == 0 && threadIdx.x < 32) zg[threadIdx.x] = (_Float16)0.f;
        int t = blockIdx.x * 256 + threadIdx.x;
        if (t >= 8 * 4608) return;
        int layer = t / 4608;
        int r = t - layer * 4608;
        int lane = r & 63, ci = r >> 6;
        int m = ci & 3, kk = (ci >> 2) & 1, s = ci >> 3;
        int o = m * 16 + (lane & 15);
        int cb = kk * 32 + ((lane >> 4) & 3) * 8;
        const float* w; int O, CIN;
        if (layer < 4)      { w = rh_w + (size_t)layer * 61 * 61 * 9; O = 61; CIN = 61; }
        else if (layer == 4){ w = hl0_w;                              O = 64; CIN = 61; }
        else                { w = hl_w + (size_t)(layer - 5) * 64 * 64 * 9; O = 64; CIN = 64; }
        half8 v;
        #pragma unroll
        for (int j = 0; j < 8; ++j) {
            int c = cb + j;
            float f = (o < O && c < CIN) ? w[((size_t)o * CIN + c) * 9 + s] : 0.f;
            v[j] = (_Float16)f;
        }
        *(half8*)(wt + (size_t)layer * 36864 + (size_t)r * 8) = v;
        return;
    }

    const int id = blockIdx.x - 144;
    const int bx = id & 31, by = (id >> 5) & 31, z = id >> 10;
    const int tx = threadIdx.x & 15, ty = threadIdx.x >> 4;
    const int ox = bx * 16 + tx, oy = by * 16 + ty;
    const int ix0 = bx * 16 - 1, iy0 = by * 16 - 1;

    for (int i = threadIdx.x; i < 3 * 324; i += 256) {
        int c = i / 324, p = i - c * 324;
        int iy = p / 18, ix = p - iy * 18;
        int gy = iy0 + iy, gx = ix0 + ix;
        float v = 0.f;
        if ((unsigned)gy < 512u && (unsigned)gx < 512u)
            v = x[(size_t)c * HW_ + (size_t)gy * 512 + gx];
        tile[i] = v;
    }
    __syncthreads();

    float p9[3][9];
    #pragma unroll
    for (int c = 0; c < 3; ++c)
        #pragma unroll
        for (int dy = 0; dy < 3; ++dy)
            #pragma unroll
            for (int dx = 0; dx < 3; ++dx)
                p9[c][dy * 3 + dx] = tile[c * 324 + (ty + dy) * 18 + tx + dx];

    float acc[16];
    #pragma unroll
    for (int o = 0; o < 16; ++o) {
        int oc = z * 16 + o;
        float a = low0_b[oc];
        const float* wo = low0_w + (size_t)oc * 27;
        #pragma unroll
        for (int c = 0; c < 3; ++c)
            #pragma unroll
            for (int k = 0; k < 9; ++k)
                a = fmaf(p9[c][k], wo[c * 9 + k], a);
        acc[o] = a;
    }

    const size_t pix = (size_t)oy * 512 + ox;
    half8 h0, h1;
    #pragma unroll
    for (int o = 0; o < 8; ++o) { h0[o] = (_Float16)acc[o]; h1[o] = (_Float16)acc[8 + o]; }
    _Float16* orow = M + pix * 64 + z * 16;
    *(half8*)(orow)     = h0;
    *(half8*)(orow + 8) = h1;
    if (z == 3) {
        #pragma unroll
        for (int o = 13; o < 16; ++o)
            L[(size_t)(o - 13) * HW_ + pix] = acc[o];
    }
}

// ---------------- MFMA implicit-GEMM conv, stride 1, 512x512 --------------
// IO: fp16 channel-interleaved [pixel][64]. LDS [p][c ^ ((p&7)<<3)].
// Activations via global_load_lds width=16. Weights double-buffered in
// 2-TAP slices (16 KB each): 5 phases / 5 barriers per layer instead of 9.
// 1-D grid 1024, bijective XCD chunk swizzle (y-band locality for halo L2).
// Epilogue transposes via in_t so global stores are dense 1 KB/wave.
// DOLH: fused 3->3 tanh conv from global (L2-resident), after epilogue.
template<int O, int ACT, int DOLH>
__global__ __launch_bounds__(256, 2)
void conv_mfma_k(const _Float16* __restrict__ in, const _Float16* __restrict__ wt,
                 const float* __restrict__ bias, _Float16* __restrict__ out,
                 const float* __restrict__ L_in, const float* __restrict__ lhw,
                 const float* __restrict__ lhb, float* __restrict__ L_out,
                 const _Float16* __restrict__ zg)
{
    __shared__ _Float16 __attribute__((aligned(16))) in_t[2592 * 8];   // 41472 B
    __shared__ _Float16 __attribute__((aligned(16))) wbuf[2][8192];    // 32768 B
    const int tid = threadIdx.x;
    const int l = tid & 63, wv = tid >> 6;
    const int px = l & 15, g = l >> 4;
    const int orig = blockIdx.x;
    const int id = ((orig & 7) << 7) + (orig >> 3);    // XCD chunk swizzle
    const int bx = id & 31, by = id >> 5;
    const int iy0 = by * 16 - 1, ix0 = bx * 16 - 1;

    // stage activations (2592 chunks) + phase-0 weights (taps 0,1: 1024 ch)
    #pragma unroll
    for (int k = 0; k < 11; ++k) {
        int i = tid + (k << 8);
        if (i < 2592) {
            int p = i >> 3, jl = i & 7;
            int iy = p / 18, ix = p - iy * 18;
            int gy = iy0 + iy, gx = ix0 + ix;
            int j = jl ^ (p & 7);
            const _Float16* src = ((unsigned)gy < 512u && (unsigned)gx < 512u)
                ? in + ((size_t)gy * 512 + gx) * 64 + j * 8 : zg;
            __builtin_amdgcn_global_load_lds(
                (const __attribute__((address_space(1))) void*)src,
                (__attribute__((address_space(3))) void*)(in_t + (size_t)(i - l) * 8),
                16, 0, 0);
        }
    }
    #pragma unroll
    for (int it = 0; it < 4; ++it) {
        int ci = (it << 8) + tid;
        __builtin_amdgcn_global_load_lds(
            (const __attribute__((address_space(1))) void*)(wt + ci * 8),
            (__attribute__((address_space(3))) void*)(wbuf[0] + (size_t)(ci - l) * 8),
            16, 0, 0);
    }
    __syncthreads();

    float bs[4][4];
    #pragma unroll
    for (int m = 0; m < 4; ++m)
        #pragma unroll
        for (int r = 0; r < 4; ++r) {
            int o = m * 16 + g * 4 + r;
            bs[m][r] = (o < O) ? bias[o] : 0.f;
        }

    f32x4 acc[4][4];
    #pragma unroll
    for (int m = 0; m < 4; ++m)
        #pragma unroll
        for (int f = 0; f < 4; ++f) acc[m][f] = (f32x4){0.f, 0.f, 0.f, 0.f};

    // 5 phases: {0,1} {2,3} {4,5} {6,7} {8}
    #pragma unroll
    for (int ph = 0; ph < 5; ++ph) {
        if (ph < 3) {            // stage taps 2ph+2, 2ph+3 -> wbuf[(ph+1)&1]
            #pragma unroll
            for (int it = 0; it < 4; ++it) {
                int ci = (it << 8) + tid;
                __builtin_amdgcn_global_load_lds(
                    (const __attribute__((address_space(1))) void*)(wt + (size_t)(ph + 1) * 8192 + ci * 8),
                    (__attribute__((address_space(3))) void*)(wbuf[(ph + 1) & 1] + (size_t)(ci - l) * 8),
                    16, 0, 0);
            }
        } else if (ph == 3) {    // stage tap 8 -> wbuf[0]
            #pragma unroll
            for (int it = 0; it < 2; ++it) {
                int ci = (it << 8) + tid;
                __builtin_amdgcn_global_load_lds(
                    (const __attribute__((address_space(1))) void*)(wt + (size_t)8 * 4096 + ci * 8),
                    (__attribute__((address_space(3))) void*)(wbuf[0] + (size_t)(ci - l) * 8),
                    16, 0, 0);
            }
        }
        const int ntap = (ph < 4) ? 2 : 1;
        const _Float16* wbb = wbuf[ph & 1];
        #pragma unroll
        for (int tl = 0; tl < ntap; ++tl) {
            const int s = 2 * ph + tl;
            const _Float16* wb = wbb + (tl << 12);
            half8 a[8];
            #pragma unroll
            for (int q = 0; q < 8; ++q)
                a[q] = *(const half8*)(wb + (q << 9) + l * 8);

            const int dy = s / 3, dx = s - dy * 3;
            #pragma unroll
            for (int f = 0; f < 4; ++f) {
                int ipix = (4 * wv + f + dy) * 18 + px + dx;
                int rb = ipix * 64, sw = (ipix & 7) << 3;
                #pragma unroll
                for (int kk = 0; kk < 2; ++kk) {
                    half8 b = *(const half8*)&in_t[rb + ((kk * 32 + g * 8) ^ sw)];
                    #pragma unroll
                    for (int m = 0; m < 4; ++m)
                        acc[m][f] = __builtin_amdgcn_mfma_f32_16x16x32_f16(
                            a[kk * 4 + m], b, acc[m][f], 0, 0, 0);
                }
            }
        }
        __syncthreads();   // wbuf[ph&1] free; next slice landed (vmcnt drain)
    }

    // ---- epilogue: transpose via LDS (reuse in_t) -> dense 1KB stores ----
    #pragma unroll
    for (int f = 0; f < 4; ++f) {
        const int p = (4 * wv + f) * 16 + px;
        const int sw = p & 7;
        #pragma unroll
        for (int m = 0; m < 4; ++m) {
            union { _Float16 h[4]; uint2 u; } pk;
            #pragma unroll
            for (int r = 0; r < 4; ++r) {
                int o = m * 16 + g * 4 + r;
                float v = acc[m][f][r] + bs[m][r];
                if (ACT) v = fmaxf(v, 0.f);
                pk.h[r] = (o < O) ? (_Float16)v : (_Float16)0.f;
            }
            int chunk = (m * 2 + (g >> 1)) ^ sw;
            *(uint2*)&in_t[p * 64 + chunk * 8 + (g & 1) * 4] = pk.u;
        }
    }
    __syncthreads();
    // pixel-linear read-back; wave stores are contiguous 1 KB.
    #pragma unroll
    for (int k = 0; k < 8; ++k) {
        int q = (k << 8) + tid;           // chunk id 0..2047
        int p = q >> 3, jc = q & 7;
        half8 v = *(const half8*)&in_t[p * 64 + ((jc ^ (p & 7)) * 8)];
        int row = p >> 4, col = p & 15;
        _Float16* dst = out + (((size_t)(by * 16 + row) * 512) + bx * 16 + col) * 64 + jc * 8;
        *(half8*)dst = v;
    }

    // fused lh: 3->3 fp32 conv + tanh (exact path), stencil from global
    if (DOLH) {
        const int tx = tid & 15, ty = tid >> 4;
        const int oy = by * 16 + ty, ox = bx * 16 + tx;
        float pv[27];
        #pragma unroll
        for (int c = 0; c < 3; ++c)
            #pragma unroll
            for (int d2 = 0; d2 < 9; ++d2) {
                int gy = oy + d2 / 3 - 1, gx = ox + d2 % 3 - 1;
                pv[c * 9 + d2] = ((unsigned)gy < 512u && (unsigned)gx < 512u)
                    ? L_in[(size_t)c * HW_ + (size_t)gy * 512 + gx] : 0.f;
            }
        const size_t pix = (size_t)oy * 512 + ox;
        #pragma unroll
        for (int oc = 0; oc < 3; ++oc) {
            float a = lhb[oc];
            #pragma unroll
            for (int k = 0; k < 27; ++k)
                a = fmaf(pv[k], lhw[oc * 27 + k], a);
            L_out[(size_t)oc * HW_ + pix] = tanhf(a);
        }
    }
}

// ---------------- MFMA stride-2 conv + relu + fused 2x2 maxpool -----------
// Per-tap LDS weight staging (9 phases, 16 KB wbuf -> 3 blocks/CU).
// NB = blocks per side; XCD swizzle only at NB=32 (1024 blocks).
template<int FP32OUT, int NB>
__global__ __launch_bounds__(256, 3)
void conv_s2_pool_k(const _Float16* __restrict__ in, int Hin,
                    const _Float16* __restrict__ wt,
                    const float* __restrict__ bias, void* __restrict__ outv,
                    const _Float16* __restrict__ zg)
{
    const int Hp = Hin >> 2;
    __shared__ _Float16 __attribute__((aligned(16))) in_t[2312 * 8];   // 36992 B
    __shared__ _Float16 __attribute__((aligned(16))) wbuf[2][4096];    // 16384 B
    const int tid = threadIdx.x;
    const int l = tid & 63, wv = tid >> 6;
    const int n = l & 15, g = l >> 4;
    int id = blockIdx.x;
    if (NB == 32) id = ((id & 7) << 7) + (id >> 3);    // XCD chunk swizzle
    const int bx = id % NB, by = id / NB;
    const int iy0 = by * 16 - 1, ix0 = bx * 16 - 1;

    #pragma unroll
    for (int k = 0; k < 10; ++k) {
        int i = tid + (k << 8);
        if (i < 2312) {
            int p = i >> 3, jl = i & 7;
            int iy = p / 17, ix = p - iy * 17;
            int gy = iy0 + iy, gx = ix0 + ix;
            int j = jl ^ (p & 7);
            const _Float16* src =
                ((unsigned)gy < (unsigned)Hin && (unsigned)gx < (unsigned)Hin)
                    ? in + ((size_t)gy * Hin + gx) * 64 + j * 8 : zg;
            __builtin_amdgcn_global_load_lds(
                (const __attribute__((address_space(1))) void*)src,
                (__attribute__((address_space(3))) void*)(in_t + (size_t)(i - l) * 8),
                16, 0, 0);
        }
    }
    #pragma unroll
    for (int it = 0; it < 2; ++it) {
        int ci = (it << 8) + tid;
        __builtin_amdgcn_global_load_lds(
            (const __attribute__((address_space(1))) void*)(wt + ci * 8),
            (__attribute__((address_space(3))) void*)(wbuf[0] + (size_t)(ci - l) * 8),
            16, 0, 0);
    }
    __syncthreads();

    float bs[4];
    #pragma unroll
    for (int r = 0; r < 4; ++r) bs[r] = bias[wv * 16 + g * 4 + r];

    f32x4 acc[4];
    #pragma unroll
    for (int f = 0; f < 4; ++f) acc[f] = (f32x4){0.f, 0.f, 0.f, 0.f};

    const int py_lo = n >> 3, pxc = n & 7;
    #pragma unroll
    for (int s = 0; s < 9; ++s) {
        if (s < 8) {
            #pragma unroll
            for (int it = 0; it < 2; ++it) {
                int ci = (it << 8) + tid;
                __builtin_amdgcn_global_load_lds(
                    (const __attribute__((address_space(1))) void*)(wt + ((s + 1) << 12) + ci * 8),
                    (__attribute__((address_space(3))) void*)(wbuf[(s + 1) & 1] + (size_t)(ci - l) * 8),
                    16, 0, 0);
            }
        }
        const _Float16* wb = wbuf[s & 1];
        half8 a[2];
        #pragma unroll
        for (int kk = 0; kk < 2; ++kk)
            a[kk] = *(const half8*)(wb + ((kk * 4 + wv) << 9) + l * 8);

        const int dy = s / 3, dx = s - dy * 3;
        #pragma unroll
        for (int f = 0; f < 4; ++f) {
            int py = 2 * f + py_lo;
            int ipix = (2 * py + dy) * 17 + 2 * pxc + dx;
            int rb = ipix * 64, sw = (ipix & 7) << 3;
            #pragma unroll
            for (int kk = 0; kk < 2; ++kk) {
                half8 b = *(const half8*)&in_t[rb + ((kk * 32 + g * 8) ^ sw)];
                acc[f] = __builtin_amdgcn_mfma_f32_16x16x32_f16(a[kk], b, acc[f], 0, 0, 0);
            }
        }
        __syncthreads();
    }

    #pragma unroll
    for (int f = 0; f < 4; ++f)
        #pragma unroll
        for (int r = 0; r < 4; ++r) {
            float v = fmaxf(acc[f][r] + bs[r], 0.f);
            v = fmaxf(v, __shfl_xor(v, 1));
            v = fmaxf(v, __shfl_xor(v, 8));
            if ((l & 9) == 0) {
                int o = wv * 16 + g * 4 + r;
                size_t pp = ((size_t)(by * 4 + f) * Hp + bx * 4 + (n >> 1)) * 64 + o;
                if (FP32OUT) ((float*)outv)[pp] = v;
                else         ((_Float16*)outv)[pp] = (_Float16)v;
            }
        }
}

// ---------------- tail ----------------------------------------------------
__global__ void meanlin_k(const float* __restrict__ h,   // [64pix][64ch] f32
                          const float* __restrict__ lw,
                          const float* __restrict__ lb,
                          float* __restrict__ wm)
{
    __shared__ float g[64];
    int t = threadIdx.x;
    if (t < 64) {
        float s = 0.f;
        for (int p = 0; p < 64; ++p) s += h[p * 64 + t];
        g[t] = s * (1.f / 64.f);
    }
    __syncthreads();
    if (t < 30) {
        float s = lb[t];
        for (int c = 0; c < 64; ++c) s = fmaf(g[c], lw[t * 64 + c], s);
        wm[t] = s;
    }
}

__global__ __launch_bounds__(256)
void final_k(const float* __restrict__ I3, const float* __restrict__ wm,
             float* __restrict__ out)
{
    __shared__ float W[30];
    if (threadIdx.x < 30) W[threadIdx.x] = wm[threadIdx.x];
    __syncthreads();
    const int HW = 512 * 512;
    for (int i = blockIdx.x * blockDim.x + threadIdx.x; i < HW;
         i += gridDim.x * blockDim.x) {
        float r = I3[i], g = I3[HW + i], b = I3[2 * HW + i];
        float f[10] = { r * r, r * g, r * b, r, g * g, g * b, g, b * b, b, 1.f };
        #pragma unroll
        for (int o = 0; o < 3; ++o) {
            float s = 0.f;
            #pragma unroll
            for (int k = 0; k < 10; ++k) s = fmaf(W[o * 10 + k], f[k], s);
            out[(size_t)o * HW + i] = s;
        }
    }
}

extern "C" void kernel_launch(void* const* d_in, const int* in_sizes, int n_in,
                              void* d_out, int out_size, void* d_ws, size_t ws_size,
                              hipStream_t stream)
{
    const float* x      = (const float*)d_in[0];
    const float* low0_w = (const float*)d_in[1];
    const float* low0_b = (const float*)d_in[2];
    const float* rh_w   = (const float*)d_in[3];
    const float* rh_b   = (const float*)d_in[4];
    const float* lh_w   = (const float*)d_in[5];
    const float* lh_b   = (const float*)d_in[6];
    const float* hl0_w  = (const float*)d_in[7];
    const float* hl0_b  = (const float*)d_in[8];
    const float* hl_w   = (const float*)d_in[9];
    const float* hl_b   = (const float*)d_in[10];
    const float* lin_w  = (const float*)d_in[11];
    const float* lin_b  = (const float*)d_in[12];
    float* out = (float*)d_out;

    const size_t HW = 512 * 512;
    _Float16* M0 = (_Float16*)d_ws;                       // [HW][64]
    _Float16* M1 = M0 + (size_t)64 * HW;
    _Float16* P0 = M1 + (size_t)64 * HW;                  // [16384][64]
    _Float16* P1 = P0 + (size_t)16384 * 64;               // [1024][64]
    _Float16* WT = P1 + (size_t)1024 * 64;                // 8*36864
    _Float16* ZG = WT + (size_t)8 * 36864;                // 32-half zero guard
    float*    P2 = (float*)(ZG + 32);                     // [64][64] f32
    float*    L0 = P2 + 64 * 64;                          // 3 fp32 planes
    float*    L1 = L0 + (size_t)3 * HW;
    float*    WM = L1 + (size_t)3 * HW;                   // 30 (pad 32)

    dim3 blk(256);

    // wtrans (blocks 0..143) + low0 (blocks 144..4239)
    pre_k<<<dim3(4240), blk, 0, stream>>>(x, low0_w, low0_b,
                                          rh_w, hl0_w, hl_w, M0, L0, WT, ZG);

    _Float16* cur = M0; _Float16* nxt = M1;
    float* Lc = L0; float* Ln = L1;
    for (int i = 0; i < 4; ++i) {
        conv_mfma_k<61, 1, 1><<<dim3(1024), blk, 0, stream>>>(
            cur, WT + (size_t)i * 36864, rh_b + i * 61, nxt,
            Lc, lh_w + (size_t)i * 81, lh_b + i * 3, Ln, ZG);
        _Float16* t = cur; cur = nxt; nxt = t;
        float* tl = Lc; Lc = Ln; Ln = tl;
    }

    // h = conv(I[:, :61]) -> 64ch fp16 interleaved
    conv_mfma_k<64, 0, 0><<<dim3(1024), blk, 0, stream>>>(
        cur, WT + (size_t)4 * 36864, hl0_b, nxt,
        nullptr, nullptr, nullptr, nullptr, ZG);

    conv_s2_pool_k<0, 32><<<dim3(1024), blk, 0, stream>>>(
        nxt, 512, WT + (size_t)5 * 36864, hl_b, (void*)P0, ZG);
    conv_s2_pool_k<0, 8><<<dim3(64), blk, 0, stream>>>(
        P0, 128, WT + (size_t)6 * 36864, hl_b + 64, (void*)P1, ZG);
    conv_s2_pool_k<1, 2><<<dim3(4), blk, 0, stream>>>(
        P1, 32, WT + (size_t)7 * 36864, hl_b + 128, (void*)P2, ZG);

    meanlin_k<<<dim3(1), dim3(64), 0, stream>>>(P2, lin_w, lin_b, WM);

    final_k<<<dim3(2048), blk, 0, stream>>>(Lc, WM, out);
}